// Round 7
// baseline (1223.865 us; speedup 1.0000x reference)
//
#include <hip/hip_runtime.h>
#include <hip/hip_bf16.h>
#include <math.h>

#define NLVL 8
#define LOG2T 19
#define TSZ (1u << LOG2T)

typedef float    f32x2 __attribute__((ext_vector_type(2)));
typedef unsigned u32x2 __attribute__((ext_vector_type(2)));

struct Scales { float s[NLVL]; };

static __device__ __forceinline__ unsigned short f2bf(float f) {
    unsigned u = __builtin_bit_cast(unsigned, f);
    u += 0x7fffu + ((u >> 16) & 1u);   // round-to-nearest-even
    return (unsigned short)(u >> 16);
}
static __device__ __forceinline__ float bfbits2f(unsigned hi16) {
    return __builtin_bit_cast(float, hi16);
}

// ---------------- Level-parallel encode, 2 points/thread ----------------
// level = blockIdx.x & 7 -> each XCD's L2 holds one 4 MB level table.
// 2 points/thread: all 16 gather indices computed first, 16 loads issued
// back-to-back -> 2x in-flight gathers per wave to saturate TA/L2.
__global__ __launch_bounds__(256) void encode_kernel2(
    const float* __restrict__ x,      // [N,3]
    const float* __restrict__ table,  // [L,T,2]
    unsigned* __restrict__ encb,      // [L][N] packed bf16x2
    int Nh, int N, Scales sc)
{
    const int lvl = blockIdx.x & 7;
    const int t = (blockIdx.x >> 3) * blockDim.x + threadIdx.x;
    if (t >= Nh) return;

    // two consecutive points: floats [6t, 6t+6)
    const f32x2* x2 = reinterpret_cast<const f32x2*>(x);
    f32x2 a = __builtin_nontemporal_load(x2 + 3 * (size_t)t + 0);
    f32x2 b = __builtin_nontemporal_load(x2 + 3 * (size_t)t + 1);
    f32x2 c = __builtin_nontemporal_load(x2 + 3 * (size_t)t + 2);
    float px[2] = { (a.x + 1.0f) * 0.5f, (b.y + 1.0f) * 0.5f };
    float py[2] = { (a.y + 1.0f) * 0.5f, (c.x + 1.0f) * 0.5f };
    float pz[2] = { (b.x + 1.0f) * 0.5f, (c.y + 1.0f) * 0.5f };

    const float s = sc.s[lvl];
    const unsigned m = TSZ - 1u;
    const f32x2* tl = reinterpret_cast<const f32x2*>(table) + (size_t)lvl * TSZ;

    unsigned idx[2][8];
    float wx[2], wy[2], wz[2];
    #pragma unroll
    for (int p = 0; p < 2; ++p) {
        float fx = fmaf(px[p], s, 0.5f);
        float fy = fmaf(py[p], s, 0.5f);
        float fz = fmaf(pz[p], s, 0.5f);
        float bx = floorf(fx), by = floorf(fy), bz = floorf(fz);
        wx[p] = fx - bx; wy[p] = fy - by; wz[p] = fz - bz;
        unsigned cx = (unsigned)bx, cy = (unsigned)by, cz = (unsigned)bz;
        unsigned hy0 = cy * 2654435761u;
        unsigned hy1 = hy0 + 2654435761u;
        unsigned hz0 = cz * 805459861u;
        unsigned hz1 = hz0 + 805459861u;
        unsigned cx1 = cx + 1u;
        idx[p][0] = (cx  ^ hy0 ^ hz0) & m;
        idx[p][1] = (cx1 ^ hy0 ^ hz0) & m;
        idx[p][2] = (cx  ^ hy1 ^ hz0) & m;
        idx[p][3] = (cx1 ^ hy1 ^ hz0) & m;
        idx[p][4] = (cx  ^ hy0 ^ hz1) & m;
        idx[p][5] = (cx1 ^ hy0 ^ hz1) & m;
        idx[p][6] = (cx  ^ hy1 ^ hz1) & m;
        idx[p][7] = (cx1 ^ hy1 ^ hz1) & m;
    }

    // issue all 16 gathers before any consumption
    f32x2 f[2][8];
    #pragma unroll
    for (int p = 0; p < 2; ++p)
        #pragma unroll
        for (int k = 0; k < 8; ++k)
            f[p][k] = tl[idx[p][k]];

    unsigned pk[2];
    #pragma unroll
    for (int p = 0; p < 2; ++p) {
        float wx0 = 1.0f - wx[p], wy0 = 1.0f - wy[p], wz0 = 1.0f - wz[p];
        float w00 = wx0 * wy0, w10 = wx[p] * wy0, w01 = wx0 * wy[p], w11 = wx[p] * wy[p];
        float a000 = w00 * wz0, a100 = w10 * wz0, a010 = w01 * wz0, a110 = w11 * wz0;
        float a001 = w00 * wz[p], a101 = w10 * wz[p], a011 = w01 * wz[p], a111 = w11 * wz[p];
        float e0 = fmaf(f[p][0].x, a000,
                   fmaf(f[p][1].x, a100,
                   fmaf(f[p][2].x, a010,
                   fmaf(f[p][3].x, a110,
                   fmaf(f[p][4].x, a001,
                   fmaf(f[p][5].x, a101,
                   fmaf(f[p][6].x, a011, f[p][7].x * a111)))))));
        float e1 = fmaf(f[p][0].y, a000,
                   fmaf(f[p][1].y, a100,
                   fmaf(f[p][2].y, a010,
                   fmaf(f[p][3].y, a110,
                   fmaf(f[p][4].y, a001,
                   fmaf(f[p][5].y, a101,
                   fmaf(f[p][6].y, a011, f[p][7].y * a111)))))));
        pk[p] = ((unsigned)f2bf(e1) << 16) | (unsigned)f2bf(e0);
    }

    u32x2 st; st.x = pk[0]; st.y = pk[1];
    __builtin_nontemporal_store(st, reinterpret_cast<u32x2*>(encb + (size_t)lvl * N) + t);
}

// ---------------- MLP pass: 16 -> 32 relu -> 1 sigmoid ----------------
__global__ __launch_bounds__(256) void mlp_kernel(
    const unsigned* __restrict__ encb,  // [L][N] packed bf16x2
    const float* __restrict__ W1,       // [16,32]
    const float* __restrict__ b1,       // [32]
    const float* __restrict__ W2,       // [32]
    const float* __restrict__ b2,       // [1]
    float* __restrict__ out, int N)
{
    int i = blockIdx.x * blockDim.x + threadIdx.x;
    if (i >= N) return;

    float enc[16];
    #pragma unroll
    for (int l = 0; l < NLVL; ++l) {
        unsigned pk = __builtin_nontemporal_load(encb + (size_t)l * N + i);
        enc[2 * l + 0] = bfbits2f(pk << 16);
        enc[2 * l + 1] = bfbits2f(pk & 0xffff0000u);
    }

    float h[32];
    #pragma unroll
    for (int j = 0; j < 32; ++j) h[j] = b1[j];
    #pragma unroll
    for (int k = 0; k < 16; ++k) {
        float e = enc[k];
        #pragma unroll
        for (int j = 0; j < 32; ++j)
            h[j] = fmaf(e, W1[k * 32 + j], h[j]);
    }
    float z = b2[0];
    #pragma unroll
    for (int j = 0; j < 32; ++j)
        z = fmaf(fmaxf(h[j], 0.0f), W2[j], z);

    out[i] = 1.0f / (1.0f + __expf(-z));
}

// ---------------- Fallback: fully fused (ws too small or odd N) ----------------
__global__ __launch_bounds__(256) void fused_kernel(
    const float* __restrict__ x, const float* __restrict__ table,
    const float* __restrict__ W1, const float* __restrict__ b1,
    const float* __restrict__ W2, const float* __restrict__ b2,
    float* __restrict__ out, int N, Scales sc)
{
    int i = blockIdx.x * blockDim.x + threadIdx.x;
    if (i >= N) return;
    float px = (x[3 * i + 0] + 1.0f) * 0.5f;
    float py = (x[3 * i + 1] + 1.0f) * 0.5f;
    float pz = (x[3 * i + 2] + 1.0f) * 0.5f;
    float enc[16];
    #pragma unroll
    for (int l = 0; l < NLVL; ++l) {
        const float s = sc.s[l];
        float fx = fmaf(px, s, 0.5f), fy = fmaf(py, s, 0.5f), fz = fmaf(pz, s, 0.5f);
        float bx = floorf(fx), by = floorf(fy), bz = floorf(fz);
        float wx = fx - bx, wy = fy - by, wz = fz - bz;
        unsigned cx = (unsigned)bx, cy = (unsigned)by, cz = (unsigned)bz;
        unsigned hy0 = cy * 2654435761u, hy1 = hy0 + 2654435761u;
        unsigned hz0 = cz * 805459861u, hz1 = hz0 + 805459861u;
        unsigned cx1 = cx + 1u;
        const unsigned m = TSZ - 1u;
        const f32x2* tl = reinterpret_cast<const f32x2*>(table) + (size_t)l * TSZ;
        f32x2 f000 = tl[(cx ^ hy0 ^ hz0) & m], f100 = tl[(cx1 ^ hy0 ^ hz0) & m];
        f32x2 f010 = tl[(cx ^ hy1 ^ hz0) & m], f110 = tl[(cx1 ^ hy1 ^ hz0) & m];
        f32x2 f001 = tl[(cx ^ hy0 ^ hz1) & m], f101 = tl[(cx1 ^ hy0 ^ hz1) & m];
        f32x2 f011 = tl[(cx ^ hy1 ^ hz1) & m], f111 = tl[(cx1 ^ hy1 ^ hz1) & m];
        float wx0 = 1.0f - wx, wy0 = 1.0f - wy, wz0 = 1.0f - wz;
        float w00 = wx0 * wy0, w10 = wx * wy0, w01 = wx0 * wy, w11 = wx * wy;
        float a000 = w00 * wz0, a100 = w10 * wz0, a010 = w01 * wz0, a110 = w11 * wz0;
        float a001 = w00 * wz, a101 = w10 * wz, a011 = w01 * wz, a111 = w11 * wz;
        enc[2*l+0] = fmaf(f000.x,a000, fmaf(f100.x,a100, fmaf(f010.x,a010, fmaf(f110.x,a110,
                     fmaf(f001.x,a001, fmaf(f101.x,a101, fmaf(f011.x,a011, f111.x*a111)))))));
        enc[2*l+1] = fmaf(f000.y,a000, fmaf(f100.y,a100, fmaf(f010.y,a010, fmaf(f110.y,a110,
                     fmaf(f001.y,a001, fmaf(f101.y,a101, fmaf(f011.y,a011, f111.y*a111)))))));
    }
    float h[32];
    #pragma unroll
    for (int j = 0; j < 32; ++j) h[j] = b1[j];
    #pragma unroll
    for (int k = 0; k < 16; ++k) {
        float e = enc[k];
        #pragma unroll
        for (int j = 0; j < 32; ++j) h[j] = fmaf(e, W1[k * 32 + j], h[j]);
    }
    float z = b2[0];
    #pragma unroll
    for (int j = 0; j < 32; ++j) z = fmaf(fmaxf(h[j], 0.0f), W2[j], z);
    out[i] = 1.0f / (1.0f + __expf(-z));
}

extern "C" void kernel_launch(void* const* d_in, const int* in_sizes, int n_in,
                              void* d_out, int out_size, void* d_ws, size_t ws_size,
                              hipStream_t stream) {
    const float* x     = (const float*)d_in[0];
    const float* table = (const float*)d_in[1];
    const float* W1    = (const float*)d_in[2];
    const float* b1    = (const float*)d_in[3];
    const float* W2    = (const float*)d_in[4];
    const float* b2    = (const float*)d_in[5];
    float* out = (float*)d_out;

    int N = in_sizes[0] / 3;

    Scales sc;
    double B = exp(log(2048.0 / 32.0) / 7.0);
    for (int l = 0; l < NLVL; ++l)
        sc.s[l] = (float)(32.0 * pow(B, (double)l) - 1.0);

    const int block = 256;
    size_t need = (size_t)NLVL * (size_t)N * sizeof(unsigned);

    if (ws_size >= need && (N % 2) == 0) {
        unsigned* encb = (unsigned*)d_ws;
        int Nh = N / 2;
        int chunks2 = (Nh + block - 1) / block;
        encode_kernel2<<<chunks2 * NLVL, block, 0, stream>>>(x, table, encb, Nh, N, sc);
        int chunks = (N + block - 1) / block;
        mlp_kernel<<<chunks, block, 0, stream>>>(encb, W1, b1, W2, b2, out, N);
    } else {
        int chunks = (N + block - 1) / block;
        fused_kernel<<<chunks, block, 0, stream>>>(x, table, W1, b1, W2, b2, out, N, sc);
    }
}

// Round 8
// 984.307 us; speedup vs baseline: 1.2434x; 1.2434x over previous
//
#include <hip/hip_runtime.h>
#include <hip/hip_bf16.h>
#include <math.h>

#define NLVL 8
#define LOG2T 19
#define TSZ (1u << LOG2T)

typedef float    f32x2 __attribute__((ext_vector_type(2)));
typedef float    f32x4 __attribute__((ext_vector_type(4)));

struct Scales { float s[NLVL]; };

static __device__ __forceinline__ unsigned short f2bf(float f) {
    unsigned u = __builtin_bit_cast(unsigned, f);
    u += 0x7fffu + ((u >> 16) & 1u);   // round-to-nearest-even
    return (unsigned short)(u >> 16);
}
static __device__ __forceinline__ float bfbits2f(unsigned hi16) {
    return __builtin_bit_cast(float, hi16);
}

// ---------------- Level-parallel encode, corner-paired gathers ----------------
// level = blockIdx.x & 7 -> each XCD's L2 holds one 4 MB level table.
// XOR-hash property: corners (cx,+y,+z) and (cx+1,+y,+z) differ only in hash
// bit0 when cx is even -> both live in one aligned 16 B pair. Always load the
// 4 aligned f32x4 pairs (covers corner cx for ALL lanes and corner cx+1 for
// even-cx lanes); only odd-cx lanes issue the 4 extra f32x2 gathers.
// Avg lines/addresses per lane-level: 8 -> 6.
__global__ __launch_bounds__(256) void encode_kernel(
    const float* __restrict__ x,      // [N,3]
    const float* __restrict__ table,  // [L,T,2]
    unsigned* __restrict__ encb,      // [L][N] packed bf16x2
    int N, Scales sc)
{
    const int lvl = blockIdx.x & 7;
    const int i = (blockIdx.x >> 3) * blockDim.x + threadIdx.x;
    if (i >= N) return;

    float xx = __builtin_nontemporal_load(x + 3 * i + 0);
    float yy = __builtin_nontemporal_load(x + 3 * i + 1);
    float zz = __builtin_nontemporal_load(x + 3 * i + 2);
    float px = (xx + 1.0f) * 0.5f;
    float py = (yy + 1.0f) * 0.5f;
    float pz = (zz + 1.0f) * 0.5f;

    const float s = sc.s[lvl];
    float fx = fmaf(px, s, 0.5f);
    float fy = fmaf(py, s, 0.5f);
    float fz = fmaf(pz, s, 0.5f);
    float bx = floorf(fx), by = floorf(fy), bz = floorf(fz);
    float wx = fx - bx, wy = fy - by, wz = fz - bz;
    unsigned cx = (unsigned)bx, cy = (unsigned)by, cz = (unsigned)bz;

    unsigned hy0 = cy * 2654435761u;
    unsigned hy1 = hy0 + 2654435761u;
    unsigned hz0 = cz * 805459861u;
    unsigned hz1 = hz0 + 805459861u;
    const unsigned m = TSZ - 1u;
    const f32x2* tl  = reinterpret_cast<const f32x2*>(table) + (size_t)lvl * TSZ;
    const f32x4* tl4 = reinterpret_cast<const f32x4*>(table + (size_t)lvl * TSZ * 2);

    // (y,z) corner combos: k=0:(y0,z0) 1:(y1,z0) 2:(y0,z1) 3:(y1,z1)
    unsigned hk[4] = { hy0 ^ hz0, hy1 ^ hz0, hy0 ^ hz1, hy1 ^ hz1 };
    unsigned i0[4], i1[4];
    #pragma unroll
    for (int k = 0; k < 4; ++k) {
        i0[k] = (cx ^ hk[k]) & m;
        i1[k] = ((cx + 1u) ^ hk[k]) & m;
    }

    // paired loads: each covers {i0[k]&~1, i0[k]|1}
    f32x4 pr[4];
    #pragma unroll
    for (int k = 0; k < 4; ++k)
        pr[k] = tl4[i0[k] >> 1];

    const bool odd = (cx & 1u) != 0u;
    f32x2 g1[4] = { {0.f,0.f}, {0.f,0.f}, {0.f,0.f}, {0.f,0.f} };
    if (odd) {
        #pragma unroll
        for (int k = 0; k < 4; ++k)
            g1[k] = tl[i1[k]];
    }

    float wx1 = wx, wx0 = 1.0f - wx;
    float wy0 = 1.0f - wy, wz0 = 1.0f - wz;
    float wyz[4] = { wy0 * wz0, wy * wz0, wy0 * wz, wy * wz };

    float e0 = 0.f, e1 = 0.f;
    #pragma unroll
    for (int k = 0; k < 4; ++k) {
        float lox = pr[k].x, loy = pr[k].y, hix = pr[k].z, hiy = pr[k].w;
        bool b0 = (i0[k] & 1u) != 0u;
        // corner (cx, k): element at i0[k] within its pair
        float f0x = b0 ? hix : lox;
        float f0y = b0 ? hiy : loy;
        // corner (cx+1, k): partner element when cx even, else the extra gather
        float pax = b0 ? lox : hix;
        float pay = b0 ? loy : hiy;
        float f1x = odd ? g1[k].x : pax;
        float f1y = odd ? g1[k].y : pay;

        float w0 = wx0 * wyz[k];
        float w1 = wx1 * wyz[k];
        e0 = fmaf(f0x, w0, fmaf(f1x, w1, e0));
        e1 = fmaf(f0y, w0, fmaf(f1y, w1, e1));
    }

    unsigned pk = ((unsigned)f2bf(e1) << 16) | (unsigned)f2bf(e0);
    __builtin_nontemporal_store(pk, encb + (size_t)lvl * N + i);
}

// ---------------- MLP pass: 16 -> 32 relu -> 1 sigmoid ----------------
__global__ __launch_bounds__(256) void mlp_kernel(
    const unsigned* __restrict__ encb,  // [L][N] packed bf16x2
    const float* __restrict__ W1,       // [16,32]
    const float* __restrict__ b1,       // [32]
    const float* __restrict__ W2,       // [32]
    const float* __restrict__ b2,       // [1]
    float* __restrict__ out, int N)
{
    int i = blockIdx.x * blockDim.x + threadIdx.x;
    if (i >= N) return;

    float enc[16];
    #pragma unroll
    for (int l = 0; l < NLVL; ++l) {
        unsigned pk = __builtin_nontemporal_load(encb + (size_t)l * N + i);
        enc[2 * l + 0] = bfbits2f(pk << 16);
        enc[2 * l + 1] = bfbits2f(pk & 0xffff0000u);
    }

    float h[32];
    #pragma unroll
    for (int j = 0; j < 32; ++j) h[j] = b1[j];
    #pragma unroll
    for (int k = 0; k < 16; ++k) {
        float e = enc[k];
        #pragma unroll
        for (int j = 0; j < 32; ++j)
            h[j] = fmaf(e, W1[k * 32 + j], h[j]);
    }
    float z = b2[0];
    #pragma unroll
    for (int j = 0; j < 32; ++j)
        z = fmaf(fmaxf(h[j], 0.0f), W2[j], z);

    out[i] = 1.0f / (1.0f + __expf(-z));
}

// ---------------- Fallback: fully fused (ws too small) ----------------
__global__ __launch_bounds__(256) void fused_kernel(
    const float* __restrict__ x, const float* __restrict__ table,
    const float* __restrict__ W1, const float* __restrict__ b1,
    const float* __restrict__ W2, const float* __restrict__ b2,
    float* __restrict__ out, int N, Scales sc)
{
    int i = blockIdx.x * blockDim.x + threadIdx.x;
    if (i >= N) return;
    float px = (x[3 * i + 0] + 1.0f) * 0.5f;
    float py = (x[3 * i + 1] + 1.0f) * 0.5f;
    float pz = (x[3 * i + 2] + 1.0f) * 0.5f;
    float enc[16];
    #pragma unroll
    for (int l = 0; l < NLVL; ++l) {
        const float s = sc.s[l];
        float fx = fmaf(px, s, 0.5f), fy = fmaf(py, s, 0.5f), fz = fmaf(pz, s, 0.5f);
        float bx = floorf(fx), by = floorf(fy), bz = floorf(fz);
        float wx = fx - bx, wy = fy - by, wz = fz - bz;
        unsigned cx = (unsigned)bx, cy = (unsigned)by, cz = (unsigned)bz;
        unsigned hy0 = cy * 2654435761u, hy1 = hy0 + 2654435761u;
        unsigned hz0 = cz * 805459861u, hz1 = hz0 + 805459861u;
        unsigned cx1 = cx + 1u;
        const unsigned m = TSZ - 1u;
        const f32x2* tl = reinterpret_cast<const f32x2*>(table) + (size_t)l * TSZ;
        f32x2 f000 = tl[(cx ^ hy0 ^ hz0) & m], f100 = tl[(cx1 ^ hy0 ^ hz0) & m];
        f32x2 f010 = tl[(cx ^ hy1 ^ hz0) & m], f110 = tl[(cx1 ^ hy1 ^ hz0) & m];
        f32x2 f001 = tl[(cx ^ hy0 ^ hz1) & m], f101 = tl[(cx1 ^ hy0 ^ hz1) & m];
        f32x2 f011 = tl[(cx ^ hy1 ^ hz1) & m], f111 = tl[(cx1 ^ hy1 ^ hz1) & m];
        float wx0 = 1.0f - wx, wy0 = 1.0f - wy, wz0 = 1.0f - wz;
        float w00 = wx0 * wy0, w10 = wx * wy0, w01 = wx0 * wy, w11 = wx * wy;
        float a000 = w00 * wz0, a100 = w10 * wz0, a010 = w01 * wz0, a110 = w11 * wz0;
        float a001 = w00 * wz, a101 = w10 * wz, a011 = w01 * wz, a111 = w11 * wz;
        enc[2*l+0] = fmaf(f000.x,a000, fmaf(f100.x,a100, fmaf(f010.x,a010, fmaf(f110.x,a110,
                     fmaf(f001.x,a001, fmaf(f101.x,a101, fmaf(f011.x,a011, f111.x*a111)))))));
        enc[2*l+1] = fmaf(f000.y,a000, fmaf(f100.y,a100, fmaf(f010.y,a010, fmaf(f110.y,a110,
                     fmaf(f001.y,a001, fmaf(f101.y,a101, fmaf(f011.y,a011, f111.y*a111)))))));
    }
    float h[32];
    #pragma unroll
    for (int j = 0; j < 32; ++j) h[j] = b1[j];
    #pragma unroll
    for (int k = 0; k < 16; ++k) {
        float e = enc[k];
        #pragma unroll
        for (int j = 0; j < 32; ++j) h[j] = fmaf(e, W1[k * 32 + j], h[j]);
    }
    float z = b2[0];
    #pragma unroll
    for (int j = 0; j < 32; ++j) z = fmaf(fmaxf(h[j], 0.0f), W2[j], z);
    out[i] = 1.0f / (1.0f + __expf(-z));
}

extern "C" void kernel_launch(void* const* d_in, const int* in_sizes, int n_in,
                              void* d_out, int out_size, void* d_ws, size_t ws_size,
                              hipStream_t stream) {
    const float* x     = (const float*)d_in[0];
    const float* table = (const float*)d_in[1];
    const float* W1    = (const float*)d_in[2];
    const float* b1    = (const float*)d_in[3];
    const float* W2    = (const float*)d_in[4];
    const float* b2    = (const float*)d_in[5];
    float* out = (float*)d_out;

    int N = in_sizes[0] / 3;

    Scales sc;
    double B = exp(log(2048.0 / 32.0) / 7.0);
    for (int l = 0; l < NLVL; ++l)
        sc.s[l] = (float)(32.0 * pow(B, (double)l) - 1.0);

    const int block = 256;
    const int chunks = (N + block - 1) / block;
    size_t need = (size_t)NLVL * (size_t)N * sizeof(unsigned);

    if (ws_size >= need) {
        unsigned* encb = (unsigned*)d_ws;
        encode_kernel<<<chunks * NLVL, block, 0, stream>>>(x, table, encb, N, sc);
        mlp_kernel<<<chunks, block, 0, stream>>>(encb, W1, b1, W2, b2, out, N);
    } else {
        fused_kernel<<<chunks, block, 0, stream>>>(x, table, W1, b1, W2, b2, out, N, sc);
    }
}